// Round 3
// baseline (19842.787 us; speedup 1.0000x reference)
//
#include <hip/hip_runtime.h>
#include <math.h>

#define BB 2048
#define TT 512
#define NFEAT 25
#define UNITS 300
#define NZ 1200
#define RPB 8
#define NT 512
#define NKS 11           // big-GEMM K-steps (352/32)
#define NTIL 80          // big-GEMM N-tiles (75 real + 5 pad)
#define TPW 10           // tiles per wave (80/8)
#define AROW 360         // Abf padded row stride (shorts)
#define HROW 328
#define GROW 72
#define ZROW 1280

#define OFF_B  0
#define SZ_B   (NTIL*NKS*512)
#define OFF_M1 (OFF_B + SZ_B)
#define SZ_M1  (4*2*512)
#define OFF_M2 (OFF_M1 + SZ_M1)
#define SZ_M2  (2*2*512)
#define OFF_H  (OFF_M2 + SZ_M2)
#define SZ_H   (2*10*512)

typedef __attribute__((ext_vector_type(4))) float f32x4;
typedef __attribute__((ext_vector_type(8))) short bf16x8;

static __device__ __forceinline__ unsigned short f2bf(float f) {
    union { float f; unsigned u; } x; x.f = f;
    unsigned r = (x.u + 0x7fffu + ((x.u >> 16) & 1u)) >> 16;
    return (unsigned short)r;
}
static __device__ __forceinline__ float ftanh(float v) {
    float e = __builtin_amdgcn_exp2f(v * 2.8853900817779268f); // e^(2v)
    return 1.f - 2.f * __builtin_amdgcn_rcpf(e + 1.f);
}

// ---- weight fragment pre-swizzle kernels ----
__global__ __launch_bounds__(256) void conv_big(
    const float* __restrict__ wk, const float* __restrict__ wr,
    unsigned short* __restrict__ dst)
{
    int idx = blockIdx.x * 256 + threadIdx.x;
    if (idx >= SZ_B) return;
    int j = idx & 7, n = (idx >> 3) & 15, kg = (idx >> 7) & 3, q = idx >> 9;
    int ks = q % NKS, nt = q / NKS;
    int k = ks * 32 + kg * 8 + j, col = nt * 16 + n;
    float v = 0.f;
    if (col < NZ) {
        if (k < 25) v = wk[k * NZ + col];
        else if (k < 325) v = wr[(k - 25) * NZ + col];
    }
    dst[OFF_B + idx] = f2bf(v);
}

__global__ __launch_bounds__(256) void conv_gen(
    const float* __restrict__ W, unsigned short* __restrict__ dst,
    int K, int N, int nks, int total)
{
    int idx = blockIdx.x * 256 + threadIdx.x;
    if (idx >= total) return;
    int j = idx & 7, n = (idx >> 3) & 15, kg = (idx >> 7) & 3, q = idx >> 9;
    int ks = q % nks, nt = q / nks;
    int k = ks * 32 + kg * 8 + j, col = nt * 16 + n;
    float v = (k < K && col < N) ? W[k * N + col] : 0.f;
    dst[idx] = f2bf(v);
}

__global__ __launch_bounds__(256) void conv_heads(
    const float* __restrict__ wa, const float* __restrict__ wm,
    const float* __restrict__ wsg, unsigned short* __restrict__ dst)
{
    int idx = blockIdx.x * 256 + threadIdx.x;
    if (idx >= SZ_H) return;
    int j = idx & 7, n = (idx >> 3) & 15, kg = (idx >> 7) & 3, q = idx >> 9;
    int ks = q % 10, nt = q / 10;
    int k = ks * 32 + kg * 8 + j, col = nt * 16 + n;
    float v = 0.f;
    if (k < 300 && col < 24) {
        int h = col >> 3, m = col & 7;
        const float* W = (h == 0) ? wa : (h == 1) ? wm : wsg;
        v = W[k * 8 + m];
    }
    dst[OFF_H + idx] = f2bf(v);
}

#define MFMA __builtin_amdgcn_mfma_f32_16x16x32_bf16

__global__ __launch_bounds__(NT, 2) void dilstm(
    const float* __restrict__ x,
    const unsigned short* __restrict__ wf,
    const float* __restrict__ bz,
    const float* __restrict__ b1v,
    const float* __restrict__ b2v,
    const float* __restrict__ ba,
    const float* __restrict__ bm,
    const float* __restrict__ bs,
    float* __restrict__ out)
{
    __shared__ unsigned short Abf[16][AROW];   // big-GEMM A (bf16): [0..23]=g, 24=comb, 25..324=h
    __shared__ unsigned short Hbf[16][HROW];   // h (bf16) for heads GEMM
    __shared__ unsigned short Gbf[16][GROW];   // gate-MLP input (bf16), K=50 pad 64
    __shared__ unsigned short G1bf[16][GROW];  // gate-MLP hidden (bf16)
    __shared__ float Zb[RPB][ZROW];
    __shared__ float Prev[RPB][NFEAT];
    __shared__ float Sc[RPB][24];
    __shared__ float Comb[RPB];

    const int t = threadIdx.x;
    const int lane = t & 63, wv = t >> 6;
    const int arow = lane & 15, akg = lane >> 4;
    const int crow0 = (lane >> 4) * 4;         // valid for lane<32
    const int row0 = blockIdx.x * RPB;

    for (int i = t; i < 16 * AROW; i += NT) ((unsigned short*)Abf)[i] = 0;
    for (int i = t; i < 16 * HROW; i += NT) ((unsigned short*)Hbf)[i] = 0;
    for (int i = t; i < 16 * GROW; i += NT) { ((unsigned short*)Gbf)[i] = 0; ((unsigned short*)G1bf)[i] = 0; }
    for (int i = t; i < RPB * NFEAT; i += NT) ((float*)Prev)[i] = 0.f;

    float creg[5] = {0.f, 0.f, 0.f, 0.f, 0.f};
    int cr[5], cu[5]; bool cact[5];
    #pragma unroll
    for (int p = 0; p < 5; ++p) {
        int idx = t + p * NT;
        cact[p] = idx < RPB * UNITS;
        cr[p] = idx / UNITS;
        cu[p] = idx - cr[p] * UNITS;
    }
    const int rA = t / 25, eA = t - (t / 25) * 25;

    float xreg = 0.f;
    if (t < 200) xreg = x[((size_t)(row0 + rA) * TT) * NFEAT + eA];
    __syncthreads();

    for (int ts = 0; ts < TT; ++ts) {
        // ---- X phase: gate-MLP input + combined ----
        if (t < 200) {
            float xv = xreg;
            if (eA < 24) {
                Gbf[rA][eA]      = f2bf(xv);
                Gbf[rA][25 + eA] = f2bf(Prev[rA][eA]);
            } else {
                float pl = Prev[rA][24];
                float comb = xv + pl;
                Comb[rA] = comb;
                float denom = fmaxf(comb, 1e-8f);
                Gbf[rA][24] = f2bf(xv / denom);
                Gbf[rA][49] = f2bf(pl / denom);
                Abf[rA][24] = f2bf(comb);
            }
        }
        __syncthreads();
        // ---- MLP layer 1 (waves 0-3, one 16-col tile each) ----
        if (wv < 4) {
            const unsigned short* bp = wf + OFF_M1 + (wv * 2) * 512 + (lane << 3);
            bf16x8 a0 = *(const bf16x8*)&Gbf[arow][akg * 8];
            bf16x8 a1 = *(const bf16x8*)&Gbf[arow][32 + akg * 8];
            bf16x8 b0 = *(const bf16x8*)(bp);
            bf16x8 b1f = *(const bf16x8*)(bp + 512);
            f32x4 acc = {0.f, 0.f, 0.f, 0.f};
            acc = MFMA(a0, b0, acc, 0, 0, 0);
            acc = MFMA(a1, b1f, acc, 0, 0, 0);
            if (lane < 32) {
                int col = wv * 16 + arow;
                if (col < 50) {
                    float bb = b1v[col];
                    #pragma unroll
                    for (int rg = 0; rg < 4; ++rg)
                        G1bf[crow0 + rg][col] = f2bf(fmaxf(acc[rg] + bb, 0.f));
                }
            }
        }
        __syncthreads();
        // ---- MLP layer 2 (waves 0-1) -> Abf[.][0..23] ----
        if (wv < 2) {
            const unsigned short* bp = wf + OFF_M2 + (wv * 2) * 512 + (lane << 3);
            bf16x8 a0 = *(const bf16x8*)&G1bf[arow][akg * 8];
            bf16x8 a1 = *(const bf16x8*)&G1bf[arow][32 + akg * 8];
            bf16x8 b0 = *(const bf16x8*)(bp);
            bf16x8 b1f = *(const bf16x8*)(bp + 512);
            f32x4 acc = {0.f, 0.f, 0.f, 0.f};
            acc = MFMA(a0, b0, acc, 0, 0, 0);
            acc = MFMA(a1, b1f, acc, 0, 0, 0);
            if (lane < 32) {
                int col = wv * 16 + arow;
                if (col < 24) {
                    float bb = b2v[col];
                    #pragma unroll
                    for (int rg = 0; rg < 4; ++rg)
                        Abf[crow0 + rg][col] = f2bf(acc[rg] + bb);
                }
            }
        }
        __syncthreads();
        // ---- big GEMM: z = Abf[16x352] @ B[352x1280], double-buffered B ----
        {
            bf16x8 af[NKS];
            #pragma unroll
            for (int ks = 0; ks < NKS; ++ks)
                af[ks] = *(const bf16x8*)&Abf[arow][ks * 32 + akg * 8];
            const unsigned short* bbase = wf + OFF_B + (lane << 3);
            bf16x8 buf[2][NKS];
            {
                const unsigned short* bp = bbase + (size_t)(wv * NKS) * 512;
                #pragma unroll
                for (int ks = 0; ks < NKS; ++ks)
                    buf[0][ks] = *(const bf16x8*)(bp + (ks << 9));
            }
            #pragma unroll
            for (int i = 0; i < TPW; ++i) {
                int nt = wv + i * 8;
                if (i + 1 < TPW) {
                    const unsigned short* bp = bbase + (size_t)((nt + 8) * NKS) * 512;
                    #pragma unroll
                    for (int ks = 0; ks < NKS; ++ks)
                        buf[(i + 1) & 1][ks] = *(const bf16x8*)(bp + (ks << 9));
                }
                f32x4 acc = {0.f, 0.f, 0.f, 0.f};
                #pragma unroll
                for (int ks = 0; ks < NKS; ++ks)
                    acc = MFMA(af[ks], buf[i & 1][ks], acc, 0, 0, 0);
                if (lane < 32) {
                    int col = nt * 16 + arow;
                    float bb = (col < NZ) ? bz[col] : 0.f;
                    #pragma unroll
                    for (int rg = 0; rg < 4; ++rg)
                        Zb[crow0 + rg][col] = acc[rg] + bb;
                }
            }
        }
        __syncthreads();
        // ---- cell (all threads) + x prefetch ----
        if (t < 200 && ts + 1 < TT)
            xreg = x[((size_t)(row0 + rA) * TT + (ts + 1)) * NFEAT + eA];
        #pragma unroll
        for (int p = 0; p < 5; ++p) if (cact[p]) {
            int r = cr[p], u = cu[p];
            float zi = Zb[r][u], zf = Zb[r][u + 300];
            float zc = Zb[r][u + 600], zo = Zb[r][u + 900];
            float ig = fminf(fmaxf(0.2f * zi + 0.5f, 0.f), 1.f);
            float fg = fminf(fmaxf(0.2f * zf + 0.5f, 0.f), 1.f);
            float og = fminf(fmaxf(0.2f * zo + 0.5f, 0.f), 1.f);
            float cn = fg * creg[p] + ig * ftanh(zc);
            creg[p] = cn;
            float hn = og * ftanh(cn);
            unsigned short hb = f2bf(hn);
            Hbf[r][u] = hb;
            Abf[r][25 + u] = hb;
        }
        __syncthreads();
        // ---- heads (waves 2-3): Sc = Hbf @ Wh + bias ----
        if (wv == 2 || wv == 3) {
            int nt = wv - 2;
            const unsigned short* bp = wf + OFF_H + (nt * 10) * 512 + (lane << 3);
            f32x4 acc = {0.f, 0.f, 0.f, 0.f};
            #pragma unroll
            for (int ks = 0; ks < 10; ++ks) {
                bf16x8 a = *(const bf16x8*)&Hbf[arow][ks * 32 + akg * 8];
                bf16x8 b = *(const bf16x8*)(bp + (ks << 9));
                acc = MFMA(a, b, acc, 0, 0, 0);
            }
            if (lane < 32) {
                int col = nt * 16 + arow;
                if (col < 24) {
                    float bb = (col < 8) ? ba[col] : (col < 16) ? bm[col - 8] : bs[col - 16];
                    #pragma unroll
                    for (int rg = 0; rg < 4; ++rg)
                        Sc[crow0 + rg][col] = acc[rg] + bb;
                }
            }
        }
        __syncthreads();
        // ---- softmax / nnelu + output ----
        if (t < 200) {
            float v;
            if (eA < 8) {
                float mx = Sc[rA][0];
                #pragma unroll
                for (int m = 1; m < 8; ++m) mx = fmaxf(mx, Sc[rA][m]);
                float sum = 0.f;
                #pragma unroll
                for (int m = 0; m < 8; ++m)
                    sum += __builtin_amdgcn_exp2f((Sc[rA][m] - mx) * 1.4426950408889634f);
                v = __builtin_amdgcn_exp2f((Sc[rA][eA] - mx) * 1.4426950408889634f) / sum;
            } else if (eA < 16) {
                v = Sc[rA][eA];
            } else if (eA < 24) {
                float s = Sc[rA][eA];
                v = (s > 0.f) ? (1.f + s) : __builtin_amdgcn_exp2f(s * 1.4426950408889634f);
            } else {
                v = Comb[rA];
            }
            Prev[rA][eA] = v;
            out[((size_t)(row0 + rA) * TT + ts) * NFEAT + eA] = v;
        }
        __syncthreads();
    }
}

extern "C" void kernel_launch(void* const* d_in, const int* in_sizes, int n_in,
                              void* d_out, int out_size, void* d_ws, size_t ws_size,
                              hipStream_t stream) {
    const float* x   = (const float*)d_in[0];
    const float* wk  = (const float*)d_in[1];
    const float* wr  = (const float*)d_in[2];
    const float* bz  = (const float*)d_in[3];
    const float* w1  = (const float*)d_in[4];
    const float* b1  = (const float*)d_in[5];
    const float* w2  = (const float*)d_in[6];
    const float* b2  = (const float*)d_in[7];
    const float* wa  = (const float*)d_in[8];
    const float* ba  = (const float*)d_in[9];
    const float* wm  = (const float*)d_in[10];
    const float* bm  = (const float*)d_in[11];
    const float* wsg = (const float*)d_in[12];
    const float* bs  = (const float*)d_in[13];
    float* out = (float*)d_out;
    unsigned short* wf = (unsigned short*)d_ws;

    conv_big<<<(SZ_B + 255) / 256, 256, 0, stream>>>(wk, wr, wf);
    conv_gen<<<(SZ_M1 + 255) / 256, 256, 0, stream>>>(w1, wf + OFF_M1, 50, 50, 2, SZ_M1);
    conv_gen<<<(SZ_M2 + 255) / 256, 256, 0, stream>>>(w2, wf + OFF_M2, 50, 24, 2, SZ_M2);
    conv_heads<<<(SZ_H + 255) / 256, 256, 0, stream>>>(wa, wm, wsg, wf);
    dilstm<<<BB / RPB, NT, 0, stream>>>(x, wf, bz, b1, b2, ba, bm, bs, out);
}

// Round 4
// 19575.952 us; speedup vs baseline: 1.0136x; 1.0136x over previous
//
#include <hip/hip_runtime.h>
#include <math.h>

#define BB 2048
#define TT 512
#define NFEAT 25
#define UNITS 300
#define NZ 1200
#define RPB 16
#define NBLK (BB / RPB)  // 128
#define NT 512
#define NKS 11           // big-GEMM K-steps (352/32)
#define NTIL 80          // big-GEMM N-tiles (75 real + 5 pad)
#define TPW 10           // tiles per wave
#define AROW 360         // Abf row stride (shorts)
#define HROW 328
#define GROW 72
#define ZROW 1284        // fp32, stride%32==4 -> 2-way max bank alias

#define OFF_B  0
#define SZ_B   (NTIL*NKS*512)
#define OFF_M1 (OFF_B + SZ_B)
#define SZ_M1  (4*2*512)
#define OFF_M2 (OFF_M1 + SZ_M1)
#define SZ_M2  (2*2*512)
#define OFF_H  (OFF_M2 + SZ_M2)
#define SZ_H   (2*10*512)

typedef __attribute__((ext_vector_type(4))) float f32x4;
typedef __attribute__((ext_vector_type(8))) short bf16x8;

static __device__ __forceinline__ unsigned short f2bf(float f) {
    union { float f; unsigned u; } x; x.f = f;
    unsigned r = (x.u + 0x7fffu + ((x.u >> 16) & 1u)) >> 16;
    return (unsigned short)r;
}
static __device__ __forceinline__ float ftanh(float v) {
    float e = __builtin_amdgcn_exp2f(v * 2.8853900817779268f); // e^(2v)
    return 1.f - 2.f * __builtin_amdgcn_rcpf(e + 1.f);
}

// ---- weight fragment pre-swizzle kernels ----
__global__ __launch_bounds__(256) void conv_big(
    const float* __restrict__ wk, const float* __restrict__ wr,
    unsigned short* __restrict__ dst)
{
    int idx = blockIdx.x * 256 + threadIdx.x;
    if (idx >= SZ_B) return;
    int j = idx & 7, n = (idx >> 3) & 15, kg = (idx >> 7) & 3, q = idx >> 9;
    int ks = q % NKS, nt = q / NKS;
    int k = ks * 32 + kg * 8 + j, col = nt * 16 + n;
    float v = 0.f;
    if (col < NZ) {
        if (k < 25) v = wk[k * NZ + col];
        else if (k < 325) v = wr[(k - 25) * NZ + col];
    }
    dst[OFF_B + idx] = f2bf(v);
}

__global__ __launch_bounds__(256) void conv_gen(
    const float* __restrict__ W, unsigned short* __restrict__ dst,
    int K, int N, int nks, int total)
{
    int idx = blockIdx.x * 256 + threadIdx.x;
    if (idx >= total) return;
    int j = idx & 7, n = (idx >> 3) & 15, kg = (idx >> 7) & 3, q = idx >> 9;
    int ks = q % nks, nt = q / nks;
    int k = ks * 32 + kg * 8 + j, col = nt * 16 + n;
    float v = (k < K && col < N) ? W[k * N + col] : 0.f;
    dst[idx] = f2bf(v);
}

__global__ __launch_bounds__(256) void conv_heads(
    const float* __restrict__ wa, const float* __restrict__ wm,
    const float* __restrict__ wsg, unsigned short* __restrict__ dst)
{
    int idx = blockIdx.x * 256 + threadIdx.x;
    if (idx >= SZ_H) return;
    int j = idx & 7, n = (idx >> 3) & 15, kg = (idx >> 7) & 3, q = idx >> 9;
    int ks = q % 10, nt = q / 10;
    int k = ks * 32 + kg * 8 + j, col = nt * 16 + n;
    float v = 0.f;
    if (k < 300 && col < 24) {
        int h = col >> 3, m = col & 7;
        const float* W = (h == 0) ? wa : (h == 1) ? wm : wsg;
        v = W[k * 8 + m];
    }
    dst[OFF_H + idx] = f2bf(v);
}

#define MFMA __builtin_amdgcn_mfma_f32_16x16x32_bf16

// One GEMM tile: prefetch NXT (tile I+1 mod TPW), MFMA on CUR, store z.
#define GSTEP(I, CUR, NXT) do {                                               \
    const unsigned short* bp_ = bbase + (size_t)((wv + (((I)+1)%TPW)*8)*NKS)*512; \
    _Pragma("unroll")                                                         \
    for (int ks = 0; ks < NKS; ++ks)                                          \
        NXT[ks] = *(const bf16x8*)(bp_ + (ks << 9));                          \
    f32x4 a0_ = {0.f,0.f,0.f,0.f}, a1_ = {0.f,0.f,0.f,0.f};                   \
    _Pragma("unroll")                                                         \
    for (int ks = 0; ks < 6; ++ks)  a0_ = MFMA(af[ks], CUR[ks], a0_, 0,0,0);  \
    _Pragma("unroll")                                                         \
    for (int ks = 6; ks < NKS; ++ks) a1_ = MFMA(af[ks], CUR[ks], a1_, 0,0,0); \
    const int col_ = (wv + (I)*8)*16 + arow;                                  \
    const float bz_ = bzr[I];                                                 \
    _Pragma("unroll")                                                         \
    for (int rg = 0; rg < 4; ++rg)                                            \
        Zb[crow0 + rg][col_] = a0_[rg] + a1_[rg] + bz_;                       \
} while (0)

__global__ __launch_bounds__(NT, 2) void dilstm(
    const float* __restrict__ x,
    const unsigned short* __restrict__ wf,
    const float* __restrict__ bz,
    const float* __restrict__ b1v,
    const float* __restrict__ b2v,
    const float* __restrict__ ba,
    const float* __restrict__ bm,
    const float* __restrict__ bs,
    float* __restrict__ out)
{
    __shared__ unsigned short Abf[16][AROW];   // [0..23]=g, 24=comb, 25..324=h, rest 0
    __shared__ unsigned short Hbf[16][HROW];   // h for heads, cols>=300 stay 0
    __shared__ unsigned short Gbf[16][GROW];   // gate-MLP input, cols>=50 stay 0
    __shared__ unsigned short G1bf[16][GROW];  // gate-MLP hidden
    __shared__ float Zb[16][ZROW];
    __shared__ float Prev[16][NFEAT];
    __shared__ float Sc[16][24];
    __shared__ float Comb[16];

    const int t = threadIdx.x;
    const int lane = t & 63, wv = t >> 6;
    const int arow = lane & 15, akg = lane >> 4;
    const int crow0 = akg * 4;               // C-fragment rows: crow0..crow0+3
    const int row0 = blockIdx.x * RPB;

    for (int i = t; i < 16 * AROW; i += NT) ((unsigned short*)Abf)[i] = 0;
    for (int i = t; i < 16 * HROW; i += NT) ((unsigned short*)Hbf)[i] = 0;
    for (int i = t; i < 16 * GROW; i += NT) { ((unsigned short*)Gbf)[i] = 0; ((unsigned short*)G1bf)[i] = 0; }
    for (int i = t; i < 16 * NFEAT; i += NT) ((float*)Prev)[i] = 0.f;

    // cell slots: 16*300 = 4800 items over 512 threads -> 10 slots
    float creg[10];
    int cr[10], cu[10]; bool cact[10];
    #pragma unroll
    for (int p = 0; p < 10; ++p) {
        int idx = t + p * NT;
        cact[p] = idx < RPB * UNITS;
        cr[p] = idx / UNITS;
        cu[p] = idx - cr[p] * UNITS;
        creg[p] = 0.f;
    }
    const int rA = t / 25, eA = t - (t / 25) * 25;

    // bias preloads
    float bzr[TPW];
    #pragma unroll
    for (int i = 0; i < TPW; ++i) {
        int col = (wv + i * 8) * 16 + arow;
        bzr[i] = (col < NZ) ? bz[col] : 0.f;
    }
    float m1b = 0.f, m2b = 0.f, hbias = 0.f;
    {
        int col = (wv & 3) * 16 + arow;
        if (wv < 4 && col < 50) m1b = b1v[col];
        if (wv < 2 && col < 24) m2b = b2v[col];
        int hc = (wv - 2) * 16 + arow;
        if ((wv == 2 || wv == 3) && hc < 24)
            hbias = (hc < 8) ? ba[hc] : (hc < 16) ? bm[hc - 8] : bs[hc - 16];
    }

    // persistent B double-buffer; prime with tile wv
    const unsigned short* bbase = wf + OFF_B + (lane << 3);
    bf16x8 bufA[NKS], bufB[NKS];
    #pragma unroll
    for (int ks = 0; ks < NKS; ++ks)
        bufA[ks] = *(const bf16x8*)(bbase + (size_t)(wv * NKS) * 512 + (ks << 9));

    float xreg = (t < 400) ? x[((size_t)(row0 + rA) * TT) * NFEAT + eA] : 0.f;
    __syncthreads();

    for (int ts = 0; ts < TT; ++ts) {
        // ---- X phase ----
        if (t < 400) {
            float xv = xreg;
            if (eA < 24) {
                Gbf[rA][eA]      = f2bf(xv);
                Gbf[rA][25 + eA] = f2bf(Prev[rA][eA]);
            } else {
                float pl = Prev[rA][24];
                float comb = xv + pl;
                Comb[rA] = comb;
                float denom = fmaxf(comb, 1e-8f);
                Gbf[rA][24] = f2bf(xv / denom);
                Gbf[rA][49] = f2bf(pl / denom);
                Abf[rA][24] = f2bf(comb);
            }
        }
        __syncthreads();
        // ---- MLP layer 1 (waves 0-3) ----
        if (wv < 4) {
            const unsigned short* bp = wf + OFF_M1 + (wv * 2) * 512 + (lane << 3);
            bf16x8 a0 = *(const bf16x8*)&Gbf[arow][akg * 8];
            bf16x8 a1 = *(const bf16x8*)&Gbf[arow][32 + akg * 8];
            bf16x8 b0 = *(const bf16x8*)(bp);
            bf16x8 b1f = *(const bf16x8*)(bp + 512);
            f32x4 acc = {0.f, 0.f, 0.f, 0.f};
            acc = MFMA(a0, b0, acc, 0, 0, 0);
            acc = MFMA(a1, b1f, acc, 0, 0, 0);
            int col = wv * 16 + arow;
            if (col < 50) {
                #pragma unroll
                for (int rg = 0; rg < 4; ++rg)
                    G1bf[crow0 + rg][col] = f2bf(fmaxf(acc[rg] + m1b, 0.f));
            }
        }
        __syncthreads();
        // ---- MLP layer 2 (waves 0-1) ----
        if (wv < 2) {
            const unsigned short* bp = wf + OFF_M2 + (wv * 2) * 512 + (lane << 3);
            bf16x8 a0 = *(const bf16x8*)&G1bf[arow][akg * 8];
            bf16x8 a1 = *(const bf16x8*)&G1bf[arow][32 + akg * 8];
            bf16x8 b0 = *(const bf16x8*)(bp);
            bf16x8 b1f = *(const bf16x8*)(bp + 512);
            f32x4 acc = {0.f, 0.f, 0.f, 0.f};
            acc = MFMA(a0, b0, acc, 0, 0, 0);
            acc = MFMA(a1, b1f, acc, 0, 0, 0);
            int col = wv * 16 + arow;
            if (col < 24) {
                #pragma unroll
                for (int rg = 0; rg < 4; ++rg)
                    Abf[crow0 + rg][col] = f2bf(acc[rg] + m2b);
            }
        }
        __syncthreads();
        // ---- big GEMM: z[16 x 1280] = Abf[16 x 352] @ B ----
        {
            bf16x8 af[NKS];
            #pragma unroll
            for (int ks = 0; ks < NKS; ++ks)
                af[ks] = *(const bf16x8*)&Abf[arow][ks * 32 + akg * 8];
            #pragma unroll
            for (int ii = 0; ii < 5; ++ii) {
                GSTEP(2 * ii,     bufA, bufB);
                GSTEP(2 * ii + 1, bufB, bufA);
            }
            // bufA now holds tile wv again -> primed for next step
        }
        __syncthreads();
        // ---- cell (all threads) + x prefetch ----
        if (t < 400 && ts + 1 < TT)
            xreg = x[((size_t)(row0 + rA) * TT + (ts + 1)) * NFEAT + eA];
        #pragma unroll
        for (int p = 0; p < 10; ++p) if (cact[p]) {
            int r = cr[p], u = cu[p];
            float zi = Zb[r][u], zf = Zb[r][u + 300];
            float zc = Zb[r][u + 600], zo = Zb[r][u + 900];
            float ig = fminf(fmaxf(0.2f * zi + 0.5f, 0.f), 1.f);
            float fg = fminf(fmaxf(0.2f * zf + 0.5f, 0.f), 1.f);
            float og = fminf(fmaxf(0.2f * zo + 0.5f, 0.f), 1.f);
            float cn = fg * creg[p] + ig * ftanh(zc);
            creg[p] = cn;
            float hn = og * ftanh(cn);
            unsigned short hb = f2bf(hn);
            Hbf[r][u] = hb;
            Abf[r][25 + u] = hb;
        }
        __syncthreads();
        // ---- heads (waves 2-3) ----
        if (wv == 2 || wv == 3) {
            int nt = wv - 2;
            const unsigned short* bp = wf + OFF_H + (nt * 10) * 512 + (lane << 3);
            f32x4 acc = {0.f, 0.f, 0.f, 0.f};
            #pragma unroll
            for (int ks = 0; ks < 10; ++ks) {
                bf16x8 a = *(const bf16x8*)&Hbf[arow][ks * 32 + akg * 8];
                bf16x8 b = *(const bf16x8*)(bp + (ks << 9));
                acc = MFMA(a, b, acc, 0, 0, 0);
            }
            int col = nt * 16 + arow;
            if (col < 24) {
                #pragma unroll
                for (int rg = 0; rg < 4; ++rg)
                    Sc[crow0 + rg][col] = acc[rg] + hbias;
            }
        }
        __syncthreads();
        // ---- softmax / nnelu + output ----
        if (t < 400) {
            float v;
            if (eA < 8) {
                float mx = Sc[rA][0];
                #pragma unroll
                for (int m = 1; m < 8; ++m) mx = fmaxf(mx, Sc[rA][m]);
                float sum = 0.f;
                #pragma unroll
                for (int m = 0; m < 8; ++m)
                    sum += __builtin_amdgcn_exp2f((Sc[rA][m] - mx) * 1.4426950408889634f);
                v = __builtin_amdgcn_exp2f((Sc[rA][eA] - mx) * 1.4426950408889634f) / sum;
            } else if (eA < 16) {
                v = Sc[rA][eA];
            } else if (eA < 24) {
                float s = Sc[rA][eA];
                v = (s > 0.f) ? (1.f + s) : __builtin_amdgcn_exp2f(s * 1.4426950408889634f);
            } else {
                v = Comb[rA];
            }
            Prev[rA][eA] = v;
            out[((size_t)(row0 + rA) * TT + ts) * NFEAT + eA] = v;
        }
        __syncthreads();
    }
}

extern "C" void kernel_launch(void* const* d_in, const int* in_sizes, int n_in,
                              void* d_out, int out_size, void* d_ws, size_t ws_size,
                              hipStream_t stream) {
    const float* x   = (const float*)d_in[0];
    const float* wk  = (const float*)d_in[1];
    const float* wr  = (const float*)d_in[2];
    const float* bz  = (const float*)d_in[3];
    const float* w1  = (const float*)d_in[4];
    const float* b1  = (const float*)d_in[5];
    const float* w2  = (const float*)d_in[6];
    const float* b2  = (const float*)d_in[7];
    const float* wa  = (const float*)d_in[8];
    const float* ba  = (const float*)d_in[9];
    const float* wm  = (const float*)d_in[10];
    const float* bm  = (const float*)d_in[11];
    const float* wsg = (const float*)d_in[12];
    const float* bs  = (const float*)d_in[13];
    float* out = (float*)d_out;
    unsigned short* wf = (unsigned short*)d_ws;

    conv_big<<<(SZ_B + 255) / 256, 256, 0, stream>>>(wk, wr, wf);
    conv_gen<<<(SZ_M1 + 255) / 256, 256, 0, stream>>>(w1, wf + OFF_M1, 50, 50, 2, SZ_M1);
    conv_gen<<<(SZ_M2 + 255) / 256, 256, 0, stream>>>(w2, wf + OFF_M2, 50, 24, 2, SZ_M2);
    conv_heads<<<(SZ_H + 255) / 256, 256, 0, stream>>>(wa, wm, wsg, wf);
    dilstm<<<NBLK, NT, 0, stream>>>(x, wf, bz, b1, b2, ba, bm, bs, out);
}

// Round 5
// 14424.603 us; speedup vs baseline: 1.3756x; 1.3571x over previous
//
#include <hip/hip_runtime.h>
#include <math.h>

#define BB 2048
#define TT 512
#define NFEAT 25
#define UNITS 300
#define RPB 32
#define NBLK (BB/RPB)    // 64
#define NT 1024
#define NKS 11           // K-steps (352/32)
#define NTIL 80          // N'-tiles (1280/16), cols >=1200 pad
#define TPW 5            // tiles per wave (80/16 waves)
#define AROW 360         // Abf row stride (shorts)
#define GROW 72

#define OFF_B  0
#define SZ_B   (NTIL*NKS*512)        // 450560
#define OFF_M1 (OFF_B + SZ_B)
#define SZ_M1  (4*2*512)             // 4096
#define OFF_M2 (OFF_M1 + SZ_M1)
#define SZ_M2  (2*2*512)             // 2048
#define OFF_H  (OFF_M2 + SZ_M2)
#define SZ_H   (2*NKS*512)           // 11264
#define SW_SZ  (SZ_M1 + SZ_M2 + SZ_H)
#define SWM1   0
#define SWM2   (SZ_M1)
#define SWH    (SZ_M1 + SZ_M2)

typedef __attribute__((ext_vector_type(4))) float f32x4;
typedef __attribute__((ext_vector_type(8))) short bf16x8;

static __device__ __forceinline__ unsigned short f2bf(float f) {
    union { float f; unsigned u; } x; x.f = f;
    unsigned r = (x.u + 0x7fffu + ((x.u >> 16) & 1u)) >> 16;
    return (unsigned short)r;
}
static __device__ __forceinline__ float ftanh(float v) {
    float e = __builtin_amdgcn_exp2f(v * 2.8853900817779268f); // e^(2v)
    return 1.f - 2.f * __builtin_amdgcn_rcpf(e + 1.f);
}

// big-GEMM B: bf16 fragments, gate-interleaved columns col' = 4*u + gate
__global__ __launch_bounds__(256) void conv_big(
    const float* __restrict__ wk, const float* __restrict__ wr,
    unsigned short* __restrict__ dst)
{
    int idx = blockIdx.x * 256 + threadIdx.x;
    if (idx >= SZ_B) return;
    int j = idx & 7, n = (idx >> 3) & 15, kg = (idx >> 7) & 3, qq = idx >> 9;
    int ks = qq % NKS, nt = qq / NKS;
    int k = ks * 32 + kg * 8 + j, c = nt * 16 + n;
    float v = 0.f;
    if (c < 1200) {
        int oc = (c & 3) * 300 + (c >> 2);
        if (k < 25)       v = wk[k * 1200 + oc];
        else if (k < 325) v = wr[(k - 25) * 1200 + oc];
    }
    dst[OFF_B + idx] = f2bf(v);
}

__global__ __launch_bounds__(256) void conv_gen(
    const float* __restrict__ W, unsigned short* __restrict__ dst,
    int K, int N, int nks, int total)
{
    int idx = blockIdx.x * 256 + threadIdx.x;
    if (idx >= total) return;
    int j = idx & 7, n = (idx >> 3) & 15, kg = (idx >> 7) & 3, qq = idx >> 9;
    int ks = qq % nks, nt = qq / nks;
    int k = ks * 32 + kg * 8 + j, col = nt * 16 + n;
    float v = (k < K && col < N) ? W[k * N + col] : 0.f;
    dst[idx] = f2bf(v);
}

// heads B with K'=352 (k' = u+25, zeros at k'<25 and k'>=325)
__global__ __launch_bounds__(256) void conv_heads(
    const float* __restrict__ wa, const float* __restrict__ wm,
    const float* __restrict__ wsg, unsigned short* __restrict__ dst)
{
    int idx = blockIdx.x * 256 + threadIdx.x;
    if (idx >= SZ_H) return;
    int j = idx & 7, n = (idx >> 3) & 15, kg = (idx >> 7) & 3, qq = idx >> 9;
    int ks = qq % NKS, nt = qq / NKS;
    int k = ks * 32 + kg * 8 + j, col = nt * 16 + n;
    float v = 0.f;
    if (k >= 25 && k < 325 && col < 24) {
        int u = k - 25, h = col >> 3, m = col & 7;
        const float* W = (h == 0) ? wa : (h == 1) ? wm : wsg;
        v = W[u * 8 + m];
    }
    dst[OFF_H + idx] = f2bf(v);
}

#define MFMA __builtin_amdgcn_mfma_f32_16x16x32_bf16

#define KSTEP(KS, CUR, NXT) do {                                              \
    if ((KS) < 10) {                                                          \
        NXT[0] = *(const bf16x8*)&Abf[p][arow][((KS)+1)*32 + akg*8];          \
        NXT[1] = *(const bf16x8*)&Abf[p][16 + arow][((KS)+1)*32 + akg*8];     \
    }                                                                         \
    _Pragma("unroll")                                                         \
    for (int i = 0; i < TPW; ++i) {                                           \
        acc[0][i] = MFMA(CUR[0], buf[i], acc[0][i], 0, 0, 0);                 \
        acc[1][i] = MFMA(CUR[1], buf[i], acc[1][i], 0, 0, 0);                 \
        buf[i] = *(const bf16x8*)(bbase +                                     \
            (size_t)(((wv + 16*i)*NKS + (((KS)+1)%NKS)) * 512));              \
    }                                                                         \
} while (0)

__global__ __launch_bounds__(NT, 4) void dilstm(
    const float* __restrict__ x,
    const unsigned short* __restrict__ wf,
    const float* __restrict__ bz,
    const float* __restrict__ b1v,
    const float* __restrict__ b2v,
    const float* __restrict__ ba,
    const float* __restrict__ bm,
    const float* __restrict__ bs,
    float* __restrict__ out)
{
    __shared__ unsigned short Abf[2][RPB][AROW]; // [0..23]=g, 24=comb, 25..324=h, 325.. = 0
    __shared__ unsigned short Gbf[RPB][GROW];    // gate-MLP input (K=50 pad 64)
    __shared__ unsigned short G1b[RPB][GROW];    // gate-MLP hidden
    __shared__ float Sc[RPB][24];
    __shared__ unsigned short SW[SW_SZ];         // staged MLP1|MLP2|heads weights

    const int t = threadIdx.x;
    const int lane = t & 63, wv = t >> 6;
    const int arow = lane & 15, akg = lane >> 4;
    const int crow0 = akg * 4;
    const int q4 = lane & 3, du = (lane >> 2) & 3;
    const int row0 = blockIdx.x * RPB;

    for (int i = t; i < 2 * RPB * AROW; i += NT) ((unsigned short*)Abf)[i] = 0;
    for (int i = t; i < RPB * GROW; i += NT) { ((unsigned short*)Gbf)[i] = 0; ((unsigned short*)G1b)[i] = 0; }
    for (int i = t; i < SW_SZ; i += NT) SW[i] = wf[OFF_M1 + i];

    // biases
    float bzr[TPW];
    #pragma unroll
    for (int i = 0; i < TPW; ++i) {
        int c = (wv + 16 * i) * 16 + arow;
        bzr[i] = (c < 1200) ? bz[(c & 3) * 300 + (c >> 2)] : 0.f;
    }
    float m1bias = 0.f, m2bias = 0.f, hbias = 0.f;
    {
        int c1 = (wv & 3) * 16 + arow;
        if (wv < 8 && c1 < 50) m1bias = b1v[c1];
        int c2 = (wv & 1) * 16 + arow;
        if (wv < 4 && c2 < 24) {
            m2bias = b2v[c2];
            hbias = (c2 < 8) ? ba[c2] : (c2 < 16) ? bm[c2 - 8] : bs[c2 - 16];
        }
    }

    float creg[2][TPW];
    #pragma unroll
    for (int m = 0; m < 2; ++m)
        #pragma unroll
        for (int i = 0; i < TPW; ++i) creg[m][i] = 0.f;

    // prime B ring (ks=0 of each owned tile)
    const unsigned short* bbase = wf + OFF_B + (lane << 3);
    bf16x8 buf[TPW];
    #pragma unroll
    for (int i = 0; i < TPW; ++i)
        buf[i] = *(const bf16x8*)(bbase + (size_t)((wv + 16 * i) * NKS) * 512);

    const int rA = t / 25, eA = t - (t / 25) * 25;
    float combreg = 0.f, xreg = 0.f;
    if (t < RPB * NFEAT) xreg = x[((size_t)(row0 + rA) * TT) * NFEAT + eA];
    __syncthreads();

    // initial gate-input build (prev = 0)
    if (t < RPB * NFEAT) {
        if (eA < 24) {
            Gbf[rA][eA] = f2bf(xreg);
        } else {
            float comb = xreg;
            combreg = comb;
            float denom = fmaxf(comb, 1e-8f);
            Gbf[rA][24] = f2bf(xreg / denom);
            Abf[0][rA][24] = f2bf(comb);
        }
    }
    __syncthreads();

    for (int ts = 0; ts < TT; ++ts) {
        const int p = ts & 1;

        // ---- MLP1 (waves 0-7: 4 col-tiles x 2 M-halves) ----
        if (wv < 8) {
            const int ct = wv & 3, mh = wv >> 2;
            bf16x8 a0 = *(const bf16x8*)&Gbf[16 * mh + arow][akg * 8];
            bf16x8 a1 = *(const bf16x8*)&Gbf[16 * mh + arow][32 + akg * 8];
            bf16x8 b0 = *(const bf16x8*)&SW[SWM1 + (ct * 2 + 0) * 512 + (lane << 3)];
            bf16x8 b1 = *(const bf16x8*)&SW[SWM1 + (ct * 2 + 1) * 512 + (lane << 3)];
            f32x4 acc1 = {0.f, 0.f, 0.f, 0.f};
            acc1 = MFMA(a0, b0, acc1, 0, 0, 0);
            acc1 = MFMA(a1, b1, acc1, 0, 0, 0);
            int col = ct * 16 + arow;
            if (col < 50) {
                #pragma unroll
                for (int rg = 0; rg < 4; ++rg)
                    G1b[16 * mh + crow0 + rg][col] = f2bf(fmaxf(acc1[rg] + m1bias, 0.f));
            }
        }
        __syncthreads();

        // ---- MLP2 (waves 0-3) -> Abf[p][.][0..23] ----
        if (wv < 4) {
            const int ct = wv & 1, mh = wv >> 1;
            bf16x8 a0 = *(const bf16x8*)&G1b[16 * mh + arow][akg * 8];
            bf16x8 a1 = *(const bf16x8*)&G1b[16 * mh + arow][32 + akg * 8];
            bf16x8 b0 = *(const bf16x8*)&SW[SWM2 + (ct * 2 + 0) * 512 + (lane << 3)];
            bf16x8 b1 = *(const bf16x8*)&SW[SWM2 + (ct * 2 + 1) * 512 + (lane << 3)];
            f32x4 acc2 = {0.f, 0.f, 0.f, 0.f};
            acc2 = MFMA(a0, b0, acc2, 0, 0, 0);
            acc2 = MFMA(a1, b1, acc2, 0, 0, 0);
            int col = ct * 16 + arow;
            if (col < 24) {
                #pragma unroll
                for (int rg = 0; rg < 4; ++rg)
                    Abf[p][16 * mh + crow0 + rg][col] = f2bf(acc2[rg] + m2bias);
            }
        }
        __syncthreads();

        // ---- big GEMM + fused cell: z then h -> Abf[p^1] ----
        {
            f32x4 acc[2][TPW];
            #pragma unroll
            for (int m = 0; m < 2; ++m)
                #pragma unroll
                for (int i = 0; i < TPW; ++i) acc[m][i] = (f32x4){0.f, 0.f, 0.f, 0.f};

            bf16x8 afA[2], afB[2];
            afA[0] = *(const bf16x8*)&Abf[p][arow][akg * 8];
            afA[1] = *(const bf16x8*)&Abf[p][16 + arow][akg * 8];

            KSTEP(0, afA, afB); KSTEP(1, afB, afA); KSTEP(2, afA, afB);
            KSTEP(3, afB, afA); KSTEP(4, afA, afB); KSTEP(5, afB, afA);
            KSTEP(6, afA, afB); KSTEP(7, afB, afA); KSTEP(8, afA, afB);
            KSTEP(9, afB, afA); KSTEP(10, afA, afB);

            if (t < RPB * NFEAT && ts + 1 < TT)
                xreg = x[((size_t)(row0 + rA) * TT + (ts + 1)) * NFEAT + eA];

            // per-tile: bias, 4-lane 4x4 transpose (gates->lanes), cell, h write
            #pragma unroll
            for (int m = 0; m < 2; ++m)
            #pragma unroll
            for (int i = 0; i < TPW; ++i) {
                float a0 = acc[m][i][0] + bzr[i];
                float a1 = acc[m][i][1] + bzr[i];
                float a2 = acc[m][i][2] + bzr[i];
                float a3 = acc[m][i][3] + bzr[i];
                float x0 = __shfl_xor(a0, 1), x1 = __shfl_xor(a1, 1);
                float x2 = __shfl_xor(a2, 1), x3 = __shfl_xor(a3, 1);
                const bool mo = (lane & 1);
                float b0 = mo ? x1 : a0, b1 = mo ? a1 : x0;
                float b2 = mo ? x3 : a2, b3 = mo ? a3 : x2;
                float y0 = __shfl_xor(b0, 2), y1 = __shfl_xor(b1, 2);
                float y2 = __shfl_xor(b2, 2), y3 = __shfl_xor(b3, 2);
                const bool m2 = (lane & 2);
                float zi = m2 ? y2 : b0, zf = m2 ? y3 : b1;
                float zc = m2 ? b2 : y0, zo = m2 ? b3 : y1;
                if (wv + 16 * i < 75) {
                    float ig = fminf(fmaxf(0.2f * zi + 0.5f, 0.f), 1.f);
                    float fg = fminf(fmaxf(0.2f * zf + 0.5f, 0.f), 1.f);
                    float og = fminf(fmaxf(0.2f * zo + 0.5f, 0.f), 1.f);
                    float cn = fg * creg[m][i] + ig * ftanh(zc);
                    creg[m][i] = cn;
                    float hn = og * ftanh(cn);
                    Abf[p ^ 1][16 * m + crow0 + q4][25 + (wv + 16 * i) * 4 + du] = f2bf(hn);
                }
            }
        }
        __syncthreads();

        // ---- heads (waves 0-3): Sc = h @ Wh + bias (K'=352, zero-padded) ----
        if (wv < 4) {
            const int ct = wv & 1, mh = wv >> 1;
            f32x4 acc3 = {0.f, 0.f, 0.f, 0.f};
            #pragma unroll
            for (int ks = 0; ks < NKS; ++ks) {
                bf16x8 a = *(const bf16x8*)&Abf[p ^ 1][16 * mh + arow][ks * 32 + akg * 8];
                bf16x8 b = *(const bf16x8*)&SW[SWH + (ct * NKS + ks) * 512 + (lane << 3)];
                acc3 = MFMA(a, b, acc3, 0, 0, 0);
            }
            int col = ct * 16 + arow;
            if (col < 24) {
                #pragma unroll
                for (int rg = 0; rg < 4; ++rg)
                    Sc[16 * mh + crow0 + rg][col] = acc3[rg] + hbias;
            }
        }
        __syncthreads();

        // ---- softmax/nnelu + out + next-step gate input ----
        if (t < RPB * NFEAT) {
            float v;
            if (eA < 8) {
                float mx = Sc[rA][0];
                #pragma unroll
                for (int m = 1; m < 8; ++m) mx = fmaxf(mx, Sc[rA][m]);
                float sum = 0.f;
                #pragma unroll
                for (int m = 0; m < 8; ++m)
                    sum += __builtin_amdgcn_exp2f((Sc[rA][m] - mx) * 1.4426950408889634f);
                v = __builtin_amdgcn_exp2f((Sc[rA][eA] - mx) * 1.4426950408889634f) / sum;
            } else if (eA < 16) {
                v = Sc[rA][eA];
            } else if (eA < 24) {
                float s = Sc[rA][eA];
                v = (s > 0.f) ? (1.f + s) : __builtin_amdgcn_exp2f(s * 1.4426950408889634f);
            } else {
                v = combreg;
            }
            out[((size_t)(row0 + rA) * TT + ts) * NFEAT + eA] = v;
            if (eA < 24) {
                Gbf[rA][eA]      = f2bf(xreg);
                Gbf[rA][25 + eA] = f2bf(v);
            } else {
                float comb = xreg + combreg;
                float denom = fmaxf(comb, 1e-8f);
                Gbf[rA][24] = f2bf(xreg / denom);
                Gbf[rA][49] = f2bf(combreg / denom);
                Abf[p ^ 1][rA][24] = f2bf(comb);
                combreg = comb;
            }
        }
        __syncthreads();
    }
}

extern "C" void kernel_launch(void* const* d_in, const int* in_sizes, int n_in,
                              void* d_out, int out_size, void* d_ws, size_t ws_size,
                              hipStream_t stream) {
    const float* x   = (const float*)d_in[0];
    const float* wk  = (const float*)d_in[1];
    const float* wr  = (const float*)d_in[2];
    const float* bz  = (const float*)d_in[3];
    const float* w1  = (const float*)d_in[4];
    const float* b1  = (const float*)d_in[5];
    const float* w2  = (const float*)d_in[6];
    const float* b2  = (const float*)d_in[7];
    const float* wa  = (const float*)d_in[8];
    const float* ba  = (const float*)d_in[9];
    const float* wm  = (const float*)d_in[10];
    const float* bm  = (const float*)d_in[11];
    const float* wsg = (const float*)d_in[12];
    const float* bs  = (const float*)d_in[13];
    float* out = (float*)d_out;
    unsigned short* wf = (unsigned short*)d_ws;

    conv_big<<<(SZ_B + 255) / 256, 256, 0, stream>>>(wk, wr, wf);
    conv_gen<<<(SZ_M1 + 255) / 256, 256, 0, stream>>>(w1, wf + OFF_M1, 50, 50, 2, SZ_M1);
    conv_gen<<<(SZ_M2 + 255) / 256, 256, 0, stream>>>(w2, wf + OFF_M2, 50, 24, 2, SZ_M2);
    conv_heads<<<(SZ_H + 255) / 256, 256, 0, stream>>>(wa, wm, wsg, wf);
    dilstm<<<NBLK, NT, 0, stream>>>(x, wf, bz, b1, b2, ba, bm, bs, out);
}